// Round 3
// baseline (444.973 us; speedup 1.0000x reference)
//
#include <hip/hip_runtime.h>
#include <math.h>

// Problem constants
constexpr int B_ = 4;
constexpr int C_ = 192;
constexpr int N_ = 3136;
constexpr int K_ = 9;
constexpr int NG = N_ / 16;     // 196 row-groups of 16
constexpr int NSPLIT = 4;       // M splits
constexpr int SPLIT = 784;      // M split width (784 = 7*112)
constexpr int BM = 112;         // cols per m-tile (7 MFMA j-groups, no masking)
constexpr int NMT = 7;          // m-tiles per split, exact

typedef _Float16 half8 __attribute__((ext_vector_type(8)));
typedef float f32x4 __attribute__((ext_vector_type(4)));
typedef unsigned long long u64;
typedef unsigned int u32;

// ---------------- norm: inv-norm + post-norm sum of squares ----------------
__global__ __launch_bounds__(256) void norm_kernel(const float* __restrict__ src,
                                                   float* __restrict__ invn,
                                                   float* __restrict__ sq) {
  int i = blockIdx.x * 256 + threadIdx.x;
  if (i >= B_ * N_) return;
  int b = i / N_, n = i - b * N_;
  const float* p = src + (size_t)b * C_ * N_ + n;
  float s = 0.f;
  for (int c = 0; c < C_; ++c) { float v = p[(size_t)c * N_]; s += v * v; }
  float d = fmaxf(sqrtf(s), 1e-12f);
  float inv = 1.0f / d;
  float s2 = 0.f;
  for (int c = 0; c < C_; ++c) { float v = p[(size_t)c * N_] * inv; s2 += v * v; }
  invn[i] = inv;
  sq[i] = s2;
}

// ------- transpose + normalize: fp32 [b][n][c] rows + f16 MFMA-swizzled -------
__global__ __launch_bounds__(256) void prep_kernel(const float* __restrict__ src,
                                                   const float* __restrict__ invn,
                                                   float* __restrict__ t32,
                                                   _Float16* __restrict__ t16sw) {
  __shared__ float tile[32 * 33];
  const int tx = threadIdx.x, ty = threadIdx.y;
  const int n0 = blockIdx.x * 32, c0 = blockIdx.y * 32, b = blockIdx.z;
  const float* sp = src + (size_t)b * C_ * N_;
#pragma unroll
  for (int i = 0; i < 4; ++i) {
    int c_loc = ty + i * 8;
    tile[c_loc * 33 + tx] = sp[(size_t)(c0 + c_loc) * N_ + n0 + tx];
  }
  __syncthreads();
#pragma unroll
  for (int i = 0; i < 4; ++i) {
    int n_loc = ty + i * 8;
    int n = n0 + n_loc;
    float v = tile[tx * 33 + n_loc] * invn[b * N_ + n];
    t32[(size_t)(b * N_ + n) * C_ + c0 + tx] = v;
  }
  int tid = ty * 32 + tx;
  if (tid < 128) {
    int n_loc = tid >> 2, cq = tid & 3;
    int n = n0 + n_loc;
    float inv = invn[b * N_ + n];
    int kc = c0 >> 5;
    int slot = (n & 15) | (cq << 4);
    half8 h;
#pragma unroll
    for (int e = 0; e < 8; ++e)
      h[e] = (_Float16)(tile[(cq * 8 + e) * 33 + n_loc] * inv);
    *(half8*)(t16sw + ((size_t)((b * NG + (n >> 4)) * 6 + kc) * 64 + slot) * 8) = h;
  }
}

// ---------------- fused f16-MFMA distance GEMM + streaming top-16 ----------------
__device__ __forceinline__ u32 fkey(float f) {
  u32 u = __float_as_uint(f);
  return u ^ (u32)(((int)u >> 31) | 0x80000000);
}

#define SWP(a, b) { u32 _lo = min(a, b); u32 _hi = max(a, b); a = _lo; b = _hi; }

#define BUBBLE(mn)                                                     \
  { K15 = mn;                                                          \
    SWP(K14, K15) SWP(K13, K14) SWP(K12, K13) SWP(K11, K12)            \
    SWP(K10, K11) SWP(K9, K10)  SWP(K8, K9)   SWP(K7, K8)              \
    SWP(K6, K7)   SWP(K5, K6)   SWP(K4, K5)   SWP(K3, K4)              \
    SWP(K2, K3)   SWP(K1, K2)   SWP(K0, K1) }

#define MERGESTEP(dist)                                                        \
  { u32 o0  = (u32)__shfl_xor((int)K15, dist), o1  = (u32)__shfl_xor((int)K14, dist); \
    u32 o2  = (u32)__shfl_xor((int)K13, dist), o3  = (u32)__shfl_xor((int)K12, dist); \
    u32 o4  = (u32)__shfl_xor((int)K11, dist), o5  = (u32)__shfl_xor((int)K10, dist); \
    u32 o6  = (u32)__shfl_xor((int)K9, dist),  o7  = (u32)__shfl_xor((int)K8, dist);  \
    u32 o8  = (u32)__shfl_xor((int)K7, dist),  o9  = (u32)__shfl_xor((int)K6, dist);  \
    u32 o10 = (u32)__shfl_xor((int)K5, dist),  o11 = (u32)__shfl_xor((int)K4, dist);  \
    u32 o12 = (u32)__shfl_xor((int)K3, dist),  o13 = (u32)__shfl_xor((int)K2, dist);  \
    u32 o14 = (u32)__shfl_xor((int)K1, dist),  o15 = (u32)__shfl_xor((int)K0, dist);  \
    K0 = min(K0, o0);   K1 = min(K1, o1);   K2 = min(K2, o2);   K3 = min(K3, o3);     \
    K4 = min(K4, o4);   K5 = min(K5, o5);   K6 = min(K6, o6);   K7 = min(K7, o7);     \
    K8 = min(K8, o8);   K9 = min(K9, o9);   K10 = min(K10, o10); K11 = min(K11, o11); \
    K12 = min(K12, o12); K13 = min(K13, o13); K14 = min(K14, o14); K15 = min(K15, o15);\
    SWP(K0, K8) SWP(K1, K9) SWP(K2, K10) SWP(K3, K11)                          \
    SWP(K4, K12) SWP(K5, K13) SWP(K6, K14) SWP(K7, K15)                        \
    SWP(K0, K4) SWP(K1, K5) SWP(K2, K6) SWP(K3, K7)                            \
    SWP(K8, K12) SWP(K9, K13) SWP(K10, K14) SWP(K11, K15)                      \
    SWP(K0, K2) SWP(K1, K3) SWP(K4, K6) SWP(K5, K7)                            \
    SWP(K8, K10) SWP(K9, K11) SWP(K12, K14) SWP(K13, K15)                      \
    SWP(K0, K1) SWP(K2, K3) SWP(K4, K5) SWP(K6, K7)                            \
    SWP(K8, K9) SWP(K10, K11) SWP(K12, K13) SWP(K14, K15) }

__global__ __launch_bounds__(256, 3) void gemm_topk(
    const _Float16* __restrict__ xsw, const _Float16* __restrict__ ysw,
    const float* __restrict__ rp, const float* __restrict__ x2a,
    const float* __restrict__ y2a, int* __restrict__ cidx) {
  __shared__ __align__(16) _Float16 As[4 * 6 * 512];   // 24 KB, resident all sweep
  __shared__ __align__(16) _Float16 Bs[2 * 7 * 512];   // 14 KB double-buffered
  __shared__ __align__(16) float scr_s[4 * 16 * 20];   // per-wave C-fragment scratch

  const int tid = threadIdx.x, w = tid >> 6, l = tid & 63;
  const int b = blockIdx.z, s = blockIdx.y, n0 = blockIdx.x * 64;

  // ---- stage A once: wave w stages its own 16-row group, all 6 k-chunks ----
  {
    const _Float16* srcA = xsw + (size_t)((b * NG + (n0 >> 4) + w) * 6) * 512;
#pragma unroll
    for (int kc = 0; kc < 6; ++kc)
      *(half8*)(As + (w * 6 + kc) * 512 + l * 8) = *(const half8*)(srcA + kc * 512 + l * 8);
  }

  auto stageB = [&](int mt, int kc, int bufn) {
    int gb = s * 49 + mt * 7;       // (s*SPLIT + mt*BM) / 16
#pragma unroll
    for (int gi = 0; gi < 2; ++gi) {
      int g = w + gi * 4;
      if (g < 7) {
        int mg = gb + g;            // <= 3*49 + 6*7 + 6 = 195 = NG-1, always valid
        *(half8*)(Bs + bufn * 3584 + g * 512 + l * 8) =
            *(const half8*)(ysw + (size_t)((b * NG + mg) * 6 + kc) * 512 + l * 8);
      }
    }
  };
  stageB(0, 0, 0);

  // per-lane streaming top-16, 32-bit packed keys: (fkey & ~0xFFF) | col_in_split
  u32 K0 = ~0u, K1 = ~0u, K2 = ~0u, K3 = ~0u, K4 = ~0u, K5 = ~0u, K6 = ~0u,
      K7 = ~0u, K8 = ~0u, K9 = ~0u, K10 = ~0u, K11 = ~0u, K12 = ~0u, K13 = ~0u,
      K14 = ~0u, K15 = ~0u;

  const int rr_ = l >> 2, qq = l & 3;           // scan role: row 0..15, col-quad
  const int colw = l & 15, rowq = (l >> 4) * 4; // C-frag role
  const int n_glob = n0 + w * 16 + rr_;
  const float x2v = x2a[b * N_ + n_glob];
  float* scr = scr_s + w * 320;

  int buf = 0;
  for (int mt = 0; mt < NMT; ++mt) {
    f32x4 acc[7];
#pragma unroll
    for (int j = 0; j < 7; ++j) acc[j] = (f32x4){0.f, 0.f, 0.f, 0.f};

    for (int kc = 0; kc < 6; ++kc) {
      __syncthreads();
      if (kc < 5) stageB(mt, kc + 1, buf ^ 1);
      else if (mt + 1 < NMT) stageB(mt + 1, 0, buf ^ 1);
      half8 a = *(const half8*)(As + (w * 6 + kc) * 512 + l * 8);
#pragma unroll
      for (int j = 0; j < 7; ++j) {
        half8 bf = *(const half8*)(Bs + buf * 3584 + j * 512 + l * 8);
        acc[j] = __builtin_amdgcn_mfma_f32_16x16x32_f16(a, bf, acc[j], 0, 0, 0);
      }
      buf ^= 1;
    }

    // ---- epilogue: per 16-col fragment group, via per-wave LDS scratch ----
    const int c0 = mt * BM;                    // col offset within split
#pragma unroll
    for (int j = 0; j < 7; ++j) {
#pragma unroll
      for (int e = 0; e < 4; ++e) scr[(rowq + e) * 20 + colw] = acc[j][e];
      f32x4 dot = *(const f32x4*)(scr + rr_ * 20 + qq * 4);
      const int cl = c0 + j * 16 + qq * 4;     // local col in split
      const int mg = s * SPLIT + cl;           // global col
      f32x4 y2v = *(const f32x4*)(y2a + b * N_ + mg);
      f32x4 rpv = *(const f32x4*)(rp + (size_t)n_glob * N_ + mg);
      float d0 = sqrtf(fmaxf(x2v + y2v[0] - 2.f * dot[0], 0.f)) + rpv[0];
      float d1 = sqrtf(fmaxf(x2v + y2v[1] - 2.f * dot[1], 0.f)) + rpv[1];
      float d2 = sqrtf(fmaxf(x2v + y2v[2] - 2.f * dot[2], 0.f)) + rpv[2];
      float d3 = sqrtf(fmaxf(x2v + y2v[3] - 2.f * dot[3], 0.f)) + rpv[3];
      u32 kk0 = (fkey(d0) & 0xFFFFF000u) | (u32)(cl + 0);
      u32 kk1 = (fkey(d1) & 0xFFFFF000u) | (u32)(cl + 1);
      u32 kk2 = (fkey(d2) & 0xFFFFF000u) | (u32)(cl + 2);
      u32 kk3 = (fkey(d3) & 0xFFFFF000u) | (u32)(cl + 3);
      u32 mn4 = min(min(kk0, kk1), min(kk2, kk3));
      if (mn4 < K15) {
        if (kk0 < K15) { BUBBLE(kk0) }
        if (kk1 < K15) { BUBBLE(kk1) }
        if (kk2 < K15) { BUBBLE(kk2) }
        if (kk3 < K15) { BUBBLE(kk3) }
      }
    }
  }

  // ---- cross-lane merge: 4 lanes per row -> row/split top-16 (bitonic) ----
  MERGESTEP(1)
  MERGESTEP(2)
  if (qq == 0) {
    int* o = cidx + ((size_t)(b * N_ + n_glob) * NSPLIT + s) * 16;
    const int base = s * SPLIT;
    o[0]  = base + (int)(K0 & 0xFFFu);  o[1]  = base + (int)(K1 & 0xFFFu);
    o[2]  = base + (int)(K2 & 0xFFFu);  o[3]  = base + (int)(K3 & 0xFFFu);
    o[4]  = base + (int)(K4 & 0xFFFu);  o[5]  = base + (int)(K5 & 0xFFFu);
    o[6]  = base + (int)(K6 & 0xFFFu);  o[7]  = base + (int)(K7 & 0xFFFu);
    o[8]  = base + (int)(K8 & 0xFFFu);  o[9]  = base + (int)(K9 & 0xFFFu);
    o[10] = base + (int)(K10 & 0xFFFu); o[11] = base + (int)(K11 & 0xFFFu);
    o[12] = base + (int)(K12 & 0xFFFu); o[13] = base + (int)(K13 & 0xFFFu);
    o[14] = base + (int)(K14 & 0xFFFu); o[15] = base + (int)(K15 & 0xFFFu);
  }
}

// ---------------- exact fp32 refine: 64 candidates -> top-9 ----------------
__global__ __launch_bounds__(256) void refine_kernel(
    const float* __restrict__ xt, const float* __restrict__ yt,
    const float* __restrict__ rp, const float* __restrict__ x2a,
    const float* __restrict__ y2a, const int* __restrict__ cidx,
    int* __restrict__ out) {
  __shared__ float vals[4][64];
  __shared__ int idxs[4][64];
  const int t = threadIdx.x, r = t >> 6, j = t & 63;
  const int b = blockIdx.y, n = blockIdx.x * 4 + r;
  int m = cidx[(size_t)(b * N_ + n) * 64 + j];
  const f32x4* xr = (const f32x4*)(xt + (size_t)(b * N_ + n) * C_);
  const f32x4* yr = (const f32x4*)(yt + (size_t)(b * N_ + m) * C_);
  f32x4 a4 = {0.f, 0.f, 0.f, 0.f};
#pragma unroll 8
  for (int c = 0; c < 48; ++c) {
    f32x4 xv = xr[c], yv = yr[c];
    a4[0] = fmaf(xv[0], yv[0], a4[0]);
    a4[1] = fmaf(xv[1], yv[1], a4[1]);
    a4[2] = fmaf(xv[2], yv[2], a4[2]);
    a4[3] = fmaf(xv[3], yv[3], a4[3]);
  }
  float acc = (a4[0] + a4[1]) + (a4[2] + a4[3]);
  float ss = x2a[b * N_ + n] + y2a[b * N_ + m] - 2.f * acc;
  float d = sqrtf(fmaxf(ss, 0.f)) + rp[(size_t)n * N_ + m];
  vals[r][j] = d;
  idxs[r][j] = m;
  __syncthreads();
  if (t < 4) {
    int n2 = blockIdx.x * 4 + t;
    int ob = (b * N_ + n2) * K_;
    float pv = -INFINITY; int pi = -1;
    for (int k = 0; k < K_; ++k) {
      float bv = INFINITY; int bi = 0x7fffffff;
      for (int q = 0; q < 64; ++q) {
        float v = vals[t][q]; int id = idxs[t][q];
        bool gt = (v > pv) || (v == pv && id > pi);
        bool lt = (v < bv) || (v == bv && id < bi);
        if (gt && lt) { bv = v; bi = id; }
      }
      out[ob + k] = bi;
      out[B_ * N_ * K_ + ob + k] = n2;
      pv = bv; pi = bi;
    }
  }
}

extern "C" void kernel_launch(void* const* d_in, const int* in_sizes, int n_in,
                              void* d_out, int out_size, void* d_ws, size_t ws_size,
                              hipStream_t stream) {
  const float* x = (const float*)d_in[0];
  const float* y = (const float*)d_in[1];
  const float* rp = (const float*)d_in[2];
  int* out = (int*)d_out;

  char* ws = (char*)d_ws;
  size_t off = 0;
  auto alloc = [&](size_t bytes) { char* p = ws + off; off += (bytes + 255) & ~(size_t)255; return p; };
  float* invnx = (float*)alloc(B_ * N_ * 4);
  float* x2 = (float*)alloc(B_ * N_ * 4);
  float* invny = (float*)alloc(B_ * N_ * 4);
  float* y2 = (float*)alloc(B_ * N_ * 4);
  float* xt32 = (float*)alloc((size_t)B_ * N_ * C_ * 4);
  float* yt32 = (float*)alloc((size_t)B_ * N_ * C_ * 4);
  _Float16* xt16 = (_Float16*)alloc((size_t)B_ * N_ * C_ * 2);
  _Float16* yt16 = (_Float16*)alloc((size_t)B_ * N_ * C_ * 2);
  int* cidx = (int*)alloc((size_t)B_ * N_ * 64 * 4);

  norm_kernel<<<(B_ * N_ + 255) / 256, 256, 0, stream>>>(x, invnx, x2);
  norm_kernel<<<(B_ * N_ + 255) / 256, 256, 0, stream>>>(y, invny, y2);
  prep_kernel<<<dim3(N_ / 32, C_ / 32, B_), dim3(32, 8), 0, stream>>>(x, invnx, xt32, xt16);
  prep_kernel<<<dim3(N_ / 32, C_ / 32, B_), dim3(32, 8), 0, stream>>>(y, invny, yt32, yt16);
  gemm_topk<<<dim3(N_ / 64, NSPLIT, B_), 256, 0, stream>>>(xt16, yt16, rp, x2, y2, cidx);
  refine_kernel<<<dim3(N_ / 4, B_), 256, 0, stream>>>(xt32, yt32, rp, x2, y2, cidx, out);
}

// Round 4
// 322.441 us; speedup vs baseline: 1.3800x; 1.3800x over previous
//
#include <hip/hip_runtime.h>
#include <math.h>

// Problem constants
constexpr int B_ = 4;
constexpr int C_ = 192;
constexpr int N_ = 3136;
constexpr int K_ = 9;
constexpr int NG = N_ / 16;     // 196 row-groups of 16
constexpr int NSPLIT = 7;       // M splits
constexpr int SPLIT = 448;      // 448 = 4*112
constexpr int BM = 112;         // cols per m-tile (7 MFMA j-groups)
constexpr int NMT = 4;          // m-tiles per split, exact

typedef _Float16 half8 __attribute__((ext_vector_type(8)));
typedef float f32x4 __attribute__((ext_vector_type(4)));
typedef unsigned long long u64;
typedef unsigned int u32;

// ---------------- norm: inv-norm + post-norm sum of squares ----------------
__global__ __launch_bounds__(256) void norm_kernel(const float* __restrict__ src,
                                                   float* __restrict__ invn,
                                                   float* __restrict__ sq) {
  int i = blockIdx.x * 256 + threadIdx.x;
  if (i >= B_ * N_) return;
  int b = i / N_, n = i - b * N_;
  const float* p = src + (size_t)b * C_ * N_ + n;
  float s = 0.f;
  for (int c = 0; c < C_; ++c) { float v = p[(size_t)c * N_]; s += v * v; }
  float d = fmaxf(sqrtf(s), 1e-12f);
  float inv = 1.0f / d;
  float s2 = 0.f;
  for (int c = 0; c < C_; ++c) { float v = p[(size_t)c * N_] * inv; s2 += v * v; }
  invn[i] = inv;
  sq[i] = s2;
}

// ------- transpose + normalize + f16 hi/lo split, MFMA-swizzled -------
// swizzle: chunk (b, g=n>>4, kc=c>>5) of 512 halves; slot = (n&15)|(((c>>3)&3)<<4);
// element = c&7 — the 16x16x32 A/B fragment lane order.
// lo is pre-scaled by 2048 so it stays in f16 normal range; hi clamped to 0
// below f16 min-normal so no MFMA input is ever a f16 denormal.
__global__ __launch_bounds__(256) void prep_kernel(const float* __restrict__ src,
                                                   const float* __restrict__ invn,
                                                   _Float16* __restrict__ hi_sw,
                                                   _Float16* __restrict__ lo_sw) {
  __shared__ float tile[32 * 33];
  const int tx = threadIdx.x, ty = threadIdx.y;
  const int n0 = blockIdx.x * 32, c0 = blockIdx.y * 32, b = blockIdx.z;
  const float* sp = src + (size_t)b * C_ * N_;
#pragma unroll
  for (int i = 0; i < 4; ++i) {
    int c_loc = ty + i * 8;
    tile[c_loc * 33 + tx] = sp[(size_t)(c0 + c_loc) * N_ + n0 + tx];
  }
  __syncthreads();
  int tid = ty * 32 + tx;
  if (tid < 128) {
    int n_loc = tid >> 2, cq = tid & 3;
    int n = n0 + n_loc;
    float inv = invn[b * N_ + n];
    int kc = c0 >> 5;
    int slot = (n & 15) | (cq << 4);
    half8 h, lo;
#pragma unroll
    for (int e = 0; e < 8; ++e) {
      float v = tile[(cq * 8 + e) * 33 + n_loc] * inv;
      _Float16 hv = (fabsf(v) < 6.1035156e-5f) ? (_Float16)0.f : (_Float16)v;
      h[e] = hv;
      lo[e] = (_Float16)((v - (float)hv) * 2048.0f);
    }
    size_t off = ((size_t)((b * NG + (n >> 4)) * 6 + kc) * 64 + slot) * 8;
    *(half8*)(hi_sw + off) = h;
    *(half8*)(lo_sw + off) = lo;
  }
}

// ---------------- fused split-f16 MFMA distance GEMM + exact streaming top-9 ----------------
__device__ __forceinline__ u32 fkey(float f) {
  u32 u = __float_as_uint(f);
  return u ^ (u32)(((int)u >> 31) | 0x80000000);
}

__device__ __forceinline__ u64 shflx(u64 v, int d) {
  int lo = __shfl_xor((int)(u32)(v & 0xffffffffull), d);
  int hi = __shfl_xor((int)(u32)(v >> 32), d);
  return ((u64)(u32)hi << 32) | (u32)lo;
}

#define SWPU(a, b) { u64 _l = (b < a) ? b : a; u64 _h = (b < a) ? a : b; a = _l; b = _h; }

#define BUBBLE9(mn)                                                    \
  { K8 = mn;                                                           \
    SWPU(K7, K8) SWPU(K6, K7) SWPU(K5, K6) SWPU(K4, K5)                \
    SWPU(K3, K4) SWPU(K2, K3) SWPU(K1, K2) SWPU(K0, K1) }

#define MERGESTEP16U(dist)                                                     \
  { u64 o0  = shflx(K15, dist), o1  = shflx(K14, dist);                        \
    u64 o2  = shflx(K13, dist), o3  = shflx(K12, dist);                        \
    u64 o4  = shflx(K11, dist), o5  = shflx(K10, dist);                        \
    u64 o6  = shflx(K9, dist),  o7  = shflx(K8, dist);                         \
    u64 o8  = shflx(K7, dist),  o9  = shflx(K6, dist);                         \
    u64 o10 = shflx(K5, dist),  o11 = shflx(K4, dist);                         \
    u64 o12 = shflx(K3, dist),  o13 = shflx(K2, dist);                         \
    u64 o14 = shflx(K1, dist),  o15 = shflx(K0, dist);                         \
    K0 = K0 < o0 ? K0 : o0;     K1 = K1 < o1 ? K1 : o1;                        \
    K2 = K2 < o2 ? K2 : o2;     K3 = K3 < o3 ? K3 : o3;                        \
    K4 = K4 < o4 ? K4 : o4;     K5 = K5 < o5 ? K5 : o5;                        \
    K6 = K6 < o6 ? K6 : o6;     K7 = K7 < o7 ? K7 : o7;                        \
    K8 = K8 < o8 ? K8 : o8;     K9 = K9 < o9 ? K9 : o9;                        \
    K10 = K10 < o10 ? K10 : o10; K11 = K11 < o11 ? K11 : o11;                  \
    K12 = K12 < o12 ? K12 : o12; K13 = K13 < o13 ? K13 : o13;                  \
    K14 = K14 < o14 ? K14 : o14; K15 = K15 < o15 ? K15 : o15;                  \
    SWPU(K0, K8) SWPU(K1, K9) SWPU(K2, K10) SWPU(K3, K11)                      \
    SWPU(K4, K12) SWPU(K5, K13) SWPU(K6, K14) SWPU(K7, K15)                    \
    SWPU(K0, K4) SWPU(K1, K5) SWPU(K2, K6) SWPU(K3, K7)                        \
    SWPU(K8, K12) SWPU(K9, K13) SWPU(K10, K14) SWPU(K11, K15)                  \
    SWPU(K0, K2) SWPU(K1, K3) SWPU(K4, K6) SWPU(K5, K7)                        \
    SWPU(K8, K10) SWPU(K9, K11) SWPU(K12, K14) SWPU(K13, K15)                  \
    SWPU(K0, K1) SWPU(K2, K3) SWPU(K4, K5) SWPU(K6, K7)                        \
    SWPU(K8, K9) SWPU(K10, K11) SWPU(K12, K13) SWPU(K14, K15) }

__global__ __launch_bounds__(256, 2) void gemm_topk(
    const _Float16* __restrict__ xh, const _Float16* __restrict__ xl,
    const _Float16* __restrict__ yh, const _Float16* __restrict__ yl,
    const float* __restrict__ rp, const float* __restrict__ x2a,
    const float* __restrict__ y2a, u64* __restrict__ cand) {
  __shared__ __align__(16) _Float16 Bs[2 * 7168];      // 7 groups x (hi,lo) x 512, dbuf
  __shared__ __align__(16) float scr_s[4 * 320];       // per-wave C-fragment scratch

  const int tid = threadIdx.x, w = tid >> 6, l = tid & 63;
  const int b = blockIdx.z, s = blockIdx.y, n0 = blockIdx.x * 64;

  // ---- A resident in registers: hi + scaled-lo, 6 k-chunks (wave owns 16 rows) ----
  half8 Ah[6], Al[6];
  {
    size_t base = (size_t)((b * NG + (n0 >> 4) + w) * 6) * 512 + (size_t)l * 8;
#pragma unroll
    for (int kc = 0; kc < 6; ++kc) {
      Ah[kc] = *(const half8*)(xh + base + kc * 512);
      Al[kc] = *(const half8*)(xl + base + kc * 512);
    }
  }

  auto stageB = [&](int mt, int kc, int bufn) {
    int gb = s * 28 + mt * 7;        // (s*SPLIT + mt*BM)/16
#pragma unroll
    for (int i = 0; i < 4; ++i) {
      int idx = tid + i * 256;       // 896 half8 chunks total (wave-uniform tail)
      if (idx < 896) {
        int g = idx >> 7, rem = idx & 127, h = rem >> 6, sl = rem & 63;
        const _Float16* srcp = h ? yl : yh;
        *(half8*)(Bs + bufn * 7168 + (g * 2 + h) * 512 + sl * 8) =
            *(const half8*)(srcp + (size_t)((b * NG + gb + g) * 6 + kc) * 512 + sl * 8);
      }
    }
  };
  stageB(0, 0, 0);

  // exact per-lane streaming top-9, u64 keys (fkey(d)<<32 | global col)
  u64 K0 = ~0ull, K1 = ~0ull, K2 = ~0ull, K3 = ~0ull, K4 = ~0ull,
      K5 = ~0ull, K6 = ~0ull, K7 = ~0ull, K8 = ~0ull;

  const int rr_ = l >> 2, qq = l & 3;            // scan role: row 0..15, col-quad
  const int colw = l & 15, rowq = (l >> 4) * 4;  // C-frag role
  const int n_glob = n0 + w * 16 + rr_;
  const float x2v = x2a[b * N_ + n_glob];
  float* scr = scr_s + w * 320;

  int buf = 0;
  for (int mt = 0; mt < NMT; ++mt) {
    f32x4 acc1[7], acc2[7];
#pragma unroll
    for (int j = 0; j < 7; ++j) {
      acc1[j] = (f32x4){0.f, 0.f, 0.f, 0.f};
      acc2[j] = (f32x4){0.f, 0.f, 0.f, 0.f};
    }

    for (int kc = 0; kc < 6; ++kc) {
      __syncthreads();
      if (kc < 5) stageB(mt, kc + 1, buf ^ 1);
      else if (mt + 1 < NMT) stageB(mt + 1, 0, buf ^ 1);
      half8 ah = Ah[kc], al = Al[kc];
#pragma unroll
      for (int j = 0; j < 7; ++j) {
        half8 bh = *(const half8*)(Bs + buf * 7168 + (j * 2) * 512 + l * 8);
        half8 bl = *(const half8*)(Bs + buf * 7168 + (j * 2 + 1) * 512 + l * 8);
        acc2[j] = __builtin_amdgcn_mfma_f32_16x16x32_f16(ah, bl, acc2[j], 0, 0, 0);
        acc2[j] = __builtin_amdgcn_mfma_f32_16x16x32_f16(al, bh, acc2[j], 0, 0, 0);
        acc1[j] = __builtin_amdgcn_mfma_f32_16x16x32_f16(ah, bh, acc1[j], 0, 0, 0);
      }
      buf ^= 1;
    }

    // ---- epilogue: combine hi/lo accs, distance, exact streaming top-9 ----
    const int c0 = mt * BM;
#pragma unroll
    for (int j = 0; j < 7; ++j) {
#pragma unroll
      for (int e = 0; e < 4; ++e)
        scr[(rowq + e) * 20 + colw] = acc1[j][e] + acc2[j][e] * (1.0f / 2048.0f);
      f32x4 dot = *(const f32x4*)(scr + rr_ * 20 + qq * 4);
      const int mg = s * SPLIT + c0 + j * 16 + qq * 4;
      f32x4 y2v = *(const f32x4*)(y2a + b * N_ + mg);
      f32x4 rpv = *(const f32x4*)(rp + (size_t)n_glob * N_ + mg);
      float d0 = sqrtf(fmaxf(x2v + y2v[0] - 2.f * dot[0], 0.f)) + rpv[0];
      float d1 = sqrtf(fmaxf(x2v + y2v[1] - 2.f * dot[1], 0.f)) + rpv[1];
      float d2 = sqrtf(fmaxf(x2v + y2v[2] - 2.f * dot[2], 0.f)) + rpv[2];
      float d3 = sqrtf(fmaxf(x2v + y2v[3] - 2.f * dot[3], 0.f)) + rpv[3];
      u64 kk0 = ((u64)fkey(d0) << 32) | (u32)(mg + 0);
      u64 kk1 = ((u64)fkey(d1) << 32) | (u32)(mg + 1);
      u64 kk2 = ((u64)fkey(d2) << 32) | (u32)(mg + 2);
      u64 kk3 = ((u64)fkey(d3) << 32) | (u32)(mg + 3);
      u64 ma = kk0 < kk1 ? kk0 : kk1;
      u64 mb = kk2 < kk3 ? kk2 : kk3;
      u64 mn = ma < mb ? ma : mb;
      if (mn < K8) {
        if (kk0 < K8) { BUBBLE9(kk0) }
        if (kk1 < K8) { BUBBLE9(kk1) }
        if (kk2 < K8) { BUBBLE9(kk2) }
        if (kk3 < K8) { BUBBLE9(kk3) }
      }
    }
  }

  // ---- cross-lane merge: 4 scan-lanes per row -> row/split top-9 (pad to 16) ----
  u64 K9 = ~0ull, K10 = ~0ull, K11 = ~0ull, K12 = ~0ull, K13 = ~0ull,
      K14 = ~0ull, K15 = ~0ull;
  MERGESTEP16U(1)
  MERGESTEP16U(2)
  if (qq == 0) {
    u64* o = cand + ((size_t)(b * N_ + n_glob) * NSPLIT + s) * 9;
    o[0] = K0; o[1] = K1; o[2] = K2; o[3] = K3; o[4] = K4;
    o[5] = K5; o[6] = K6; o[7] = K7; o[8] = K8;
  }
}

// ---------------- merge across splits: 63 exact keys -> top-9 ----------------
__global__ __launch_bounds__(256) void merge_kernel(const u64* __restrict__ cand,
                                                    int* __restrict__ out) {
  int r = blockIdx.x * 256 + threadIdx.x;   // row id, 12544 total (grid exact)
  int n = r % N_;
  const u64* c = cand + (size_t)r * (NSPLIT * 9);
  u64 K0 = ~0ull, K1 = ~0ull, K2 = ~0ull, K3 = ~0ull, K4 = ~0ull,
      K5 = ~0ull, K6 = ~0ull, K7 = ~0ull, K8 = ~0ull;
  for (int i = 0; i < NSPLIT * 9; ++i) {
    u64 kk = c[i];
    if (kk < K8) { BUBBLE9(kk) }
  }
  int ob = r * K_;
  out[ob + 0] = (int)(u32)K0; out[ob + 1] = (int)(u32)K1;
  out[ob + 2] = (int)(u32)K2; out[ob + 3] = (int)(u32)K3;
  out[ob + 4] = (int)(u32)K4; out[ob + 5] = (int)(u32)K5;
  out[ob + 6] = (int)(u32)K6; out[ob + 7] = (int)(u32)K7;
  out[ob + 8] = (int)(u32)K8;
  int* oc = out + B_ * N_ * K_ + ob;
#pragma unroll
  for (int k = 0; k < K_; ++k) oc[k] = n;
}

extern "C" void kernel_launch(void* const* d_in, const int* in_sizes, int n_in,
                              void* d_out, int out_size, void* d_ws, size_t ws_size,
                              hipStream_t stream) {
  const float* x = (const float*)d_in[0];
  const float* y = (const float*)d_in[1];
  const float* rp = (const float*)d_in[2];
  int* out = (int*)d_out;

  char* ws = (char*)d_ws;
  size_t off = 0;
  auto alloc = [&](size_t bytes) { char* p = ws + off; off += (bytes + 255) & ~(size_t)255; return p; };
  float* invnx = (float*)alloc(B_ * N_ * 4);
  float* x2 = (float*)alloc(B_ * N_ * 4);
  float* invny = (float*)alloc(B_ * N_ * 4);
  float* y2 = (float*)alloc(B_ * N_ * 4);
  _Float16* xh = (_Float16*)alloc((size_t)B_ * N_ * C_ * 2);
  _Float16* xl = (_Float16*)alloc((size_t)B_ * N_ * C_ * 2);
  _Float16* yh = (_Float16*)alloc((size_t)B_ * N_ * C_ * 2);
  _Float16* yl = (_Float16*)alloc((size_t)B_ * N_ * C_ * 2);
  u64* cand = (u64*)alloc((size_t)B_ * N_ * NSPLIT * 9 * 8);

  norm_kernel<<<(B_ * N_ + 255) / 256, 256, 0, stream>>>(x, invnx, x2);
  norm_kernel<<<(B_ * N_ + 255) / 256, 256, 0, stream>>>(y, invny, y2);
  prep_kernel<<<dim3(N_ / 32, C_ / 32, B_), dim3(32, 8), 0, stream>>>(x, invnx, xh, xl);
  prep_kernel<<<dim3(N_ / 32, C_ / 32, B_), dim3(32, 8), 0, stream>>>(y, invny, yh, yl);
  gemm_topk<<<dim3(N_ / 64, NSPLIT, B_), 256, 0, stream>>>(xh, xl, yh, yl, rp, x2, y2, cand);
  merge_kernel<<<B_ * N_ / 256, 256, 0, stream>>>(cand, out);
}